// Round 2
// baseline (204.702 us; speedup 1.0000x reference)
//
#include <hip/hip_runtime.h>
#include <stdint.h>

#define NQ 8192
#define NK 8192
#define DIN 32

#define CHUNK 1024
#define BT 256                 // threads per block (4 waves)
#define RPW 4                  // q-rows per wave
#define WAVES (BT / 64)
#define ROWS_PER_BLOCK (WAVES * RPW)   // 16

// ---------------- threefry2x32-20, JAX partitionable path ----------------
// key = jax.random.key(42) -> (k1,k2) = (0, 42)
// per-element counter (hi,lo) = (0, flat_idx); output = out0 ^ out1
__device__ __forceinline__ uint32_t rotl32(uint32_t v, int d) {
    return (v << d) | (v >> (32 - d));
}

__device__ __forceinline__ uint32_t threefry_fold(uint32_t idx) {
    const uint32_t ks1 = 42u;
    const uint32_t ks2 = 0x1BD11BDAu ^ 42u;   // k0 ^ k1 ^ 0x1BD11BDA, k0 = 0
    uint32_t x0 = 0u;            // counts_hi(0) + ks0(0)
    uint32_t x1 = idx + ks1;     // counts_lo + ks1
#define TFR4(a, b, c, d)                                  \
    x0 += x1; x1 = rotl32(x1, a); x1 ^= x0;               \
    x0 += x1; x1 = rotl32(x1, b); x1 ^= x0;               \
    x0 += x1; x1 = rotl32(x1, c); x1 ^= x0;               \
    x0 += x1; x1 = rotl32(x1, d); x1 ^= x0;
    TFR4(13, 15, 26, 6)
    x0 += ks1; x1 += ks2 + 1u;
    TFR4(17, 29, 16, 24)
    x0 += ks2; x1 += 0u + 2u;
    TFR4(13, 15, 26, 6)
    x0 += 0u;  x1 += ks1 + 3u;
    TFR4(17, 29, 16, 24)
    x0 += ks1; x1 += ks2 + 4u;
    TFR4(13, 15, 26, 6)
    x0 += ks2; x1 += 0u + 5u;
#undef TFR4
    return x0 ^ x1;
}

// keep  <=>  uniform < 0.8f  <=>  (bits >> 9) * 2^-23 < 0.8f  <=>  (bits>>9) < 6710887
#define KEEP_THRESH 6710887u

// ---------------- tiny projection: out[r][c] = x[r][:] . w[c][:] + b[c] --
__global__ void proj_kernel(const float* __restrict__ x,
                            const float* __restrict__ w,
                            const float* __restrict__ b,
                            float* __restrict__ out, int dout) {
    __shared__ __align__(16) float ws[8 * DIN];
    __shared__ float bs[8];
    const int tid = threadIdx.x;
    if (tid < dout * DIN) ws[tid] = w[tid];
    if (tid < dout) bs[tid] = b[tid];
    __syncthreads();

    const int row = blockIdx.x * BT + tid;
    const float4* xr = reinterpret_cast<const float4*>(x + (size_t)row * DIN);
    float4 xv[8];
#pragma unroll
    for (int i = 0; i < 8; ++i) xv[i] = xr[i];

    for (int c = 0; c < dout; ++c) {
        float s = bs[c];
#pragma unroll
        for (int i = 0; i < 8; ++i) {
            const float4 wv = *reinterpret_cast<const float4*>(&ws[c * DIN + i * 4]);
            s += xv[i].x * wv.x + xv[i].y * wv.y + xv[i].z * wv.z + xv[i].w * wv.w;
        }
        out[(size_t)row * dout + c] = s;
    }
}

// ---------------- fused scores+softmax+dropout+PV ------------------------
__global__ __launch_bounds__(BT) void attn_kernel(
    const float* __restrict__ q,   // [NQ][4]
    const float* __restrict__ k,   // [NK][4]
    const float* __restrict__ v,   // [NK][8]
    float* __restrict__ out) {     // [NQ][8]
    __shared__ float4 lds_k[CHUNK];
    __shared__ float4 lds_va[CHUNK];
    __shared__ float4 lds_vb[CHUNK];

    const int tid = threadIdx.x;
    const int lane = tid & 63;
    const int wave = tid >> 6;
    const int qbase = blockIdx.x * ROWS_PER_BLOCK + wave * RPW;

    float4 qr[RPW];
#pragma unroll
    for (int r = 0; r < RPW; ++r)
        qr[r] = *reinterpret_cast<const float4*>(q + (size_t)(qbase + r) * 4);

    float4 accA[RPW], accB[RPW];
    float den[RPW];
#pragma unroll
    for (int r = 0; r < RPW; ++r) {
        accA[r] = make_float4(0.f, 0.f, 0.f, 0.f);
        accB[r] = make_float4(0.f, 0.f, 0.f, 0.f);
        den[r] = 0.f;
    }

    const float4* ksrc = reinterpret_cast<const float4*>(k);
    const float4* vsrc = reinterpret_cast<const float4*>(v);

    for (int base = 0; base < NK; base += CHUNK) {
        __syncthreads();
#pragma unroll
        for (int i = tid; i < CHUNK; i += BT) {
            lds_k[i]  = ksrc[base + i];
            lds_va[i] = vsrc[2 * (base + i)];
            lds_vb[i] = vsrc[2 * (base + i) + 1];
        }
        __syncthreads();

        for (int kk = lane; kk < CHUNK; kk += 64) {
            const float4 kv = lds_k[kk];
            const float4 va = lds_va[kk];
            const float4 vb = lds_vb[kk];
            const uint32_t idx0 =
                (uint32_t)qbase * (uint32_t)NK + (uint32_t)(base + kk);
#pragma unroll
            for (int r = 0; r < RPW; ++r) {
                const float s = (qr[r].x * kv.x + qr[r].y * kv.y +
                                 qr[r].z * kv.z + qr[r].w * kv.w) * 0.0625f;
                const float e = __expf(s);
                const uint32_t bits = threefry_fold(idx0 + (uint32_t)r * (uint32_t)NK);
                const uint32_t m = bits >> 9;
                const float w = (m < KEEP_THRESH) ? e : 0.0f;
                den[r] += e;
                accA[r].x += w * va.x; accA[r].y += w * va.y;
                accA[r].z += w * va.z; accA[r].w += w * va.w;
                accB[r].x += w * vb.x; accB[r].y += w * vb.y;
                accB[r].z += w * vb.z; accB[r].w += w * vb.w;
            }
        }
    }

    // wave-level reduction of 9 accumulators per row
#pragma unroll
    for (int r = 0; r < RPW; ++r) {
        float n0 = accA[r].x, n1 = accA[r].y, n2 = accA[r].z, n3 = accA[r].w;
        float n4 = accB[r].x, n5 = accB[r].y, n6 = accB[r].z, n7 = accB[r].w;
        float dd = den[r];
#pragma unroll
        for (int off = 32; off >= 1; off >>= 1) {
            n0 += __shfl_xor(n0, off); n1 += __shfl_xor(n1, off);
            n2 += __shfl_xor(n2, off); n3 += __shfl_xor(n3, off);
            n4 += __shfl_xor(n4, off); n5 += __shfl_xor(n5, off);
            n6 += __shfl_xor(n6, off); n7 += __shfl_xor(n7, off);
            dd += __shfl_xor(dd, off);
        }
        if (lane == 0) {
            const float inv = 1.0f / (0.8f * dd);
            float4* op = reinterpret_cast<float4*>(out + (size_t)(qbase + r) * 8);
            op[0] = make_float4(n0 * inv, n1 * inv, n2 * inv, n3 * inv);
            op[1] = make_float4(n4 * inv, n5 * inv, n6 * inv, n7 * inv);
        }
    }
}

extern "C" void kernel_launch(void* const* d_in, const int* in_sizes, int n_in,
                              void* d_out, int out_size, void* d_ws, size_t ws_size,
                              hipStream_t stream) {
    const float* x1   = (const float*)d_in[0];
    const float* x2   = (const float*)d_in[1];
    const float* wq_w = (const float*)d_in[2];
    const float* wq_b = (const float*)d_in[3];
    const float* wk_w = (const float*)d_in[4];
    const float* wk_b = (const float*)d_in[5];
    const float* wv_w = (const float*)d_in[6];
    const float* wv_b = (const float*)d_in[7];
    float* out = (float*)d_out;

    // workspace layout: q [8192*4] | k [8192*4] | v [8192*8]  (512 KB total)
    float* qws = (float*)d_ws;
    float* kws = qws + (size_t)NQ * 4;
    float* vws = kws + (size_t)NK * 4;

    proj_kernel<<<NQ / BT, BT, 0, stream>>>(x1, wq_w, wq_b, qws, 4);
    proj_kernel<<<NK / BT, BT, 0, stream>>>(x2, wk_w, wk_b, kws, 4);
    proj_kernel<<<NK / BT, BT, 0, stream>>>(x2, wv_w, wv_b, vws, 8);

    attn_kernel<<<NQ / ROWS_PER_BLOCK, BT, 0, stream>>>(qws, kws, vws, out);
}

// Round 3
// 198.221 us; speedup vs baseline: 1.0327x; 1.0327x over previous
//
#include <hip/hip_runtime.h>
#include <stdint.h>

#define NQ 8192
#define NK 8192
#define DIN 32

#define BT 256                 // threads per block (4 waves)
#define RPW 4                  // q-rows per wave (4 interleaved hash chains)
#define ROWS_PER_BLOCK 16      // 4 waves * RPW
#define CHUNK 512              // k rows staged in LDS per iteration

// keep  <=>  (bits >> 9) < 6710887  <=>  bits < 6710887*512
#define KEEP_BITS 3435974144u
// fold 1/16 (scores scale) and log2(e) into q so e = exp2(dot(qs, k))
#define QSCALE 0.0901684060119172f

// ---------------- threefry2x32-20, JAX partitionable path ----------------
// key = jax.random.key(42) -> (0, 42); counter (hi,lo) = (0, flat_idx)
// bits = out0 ^ out1. Verified bit-exact in round 2.
__device__ __forceinline__ uint32_t rotl(uint32_t v, int d) {
    return __builtin_amdgcn_alignbit(v, v, 32 - d);   // 1 VALU op
}

__device__ __forceinline__ void round4(uint32_t x0[4], uint32_t x1[4], int d) {
#pragma unroll
    for (int j = 0; j < 4; ++j) {
        x0[j] += x1[j];
        x1[j] = rotl(x1[j], d);
        x1[j] ^= x0[j];
    }
}

__device__ __forceinline__ void inject4(uint32_t x0[4], uint32_t x1[4],
                                        uint32_t c0, uint32_t c1) {
#pragma unroll
    for (int j = 0; j < 4; ++j) { x0[j] += c0; x1[j] += c1; }
}

// 4 independent hashes for counters idx0 + j*NK  (j = row index within wave)
__device__ __forceinline__ void threefry4(uint32_t idx0, uint32_t bits[4]) {
    const uint32_t ks1 = 42u;
    const uint32_t ks2 = 0x1BD11BDAu ^ 42u;
    uint32_t x0[4], x1[4];
#pragma unroll
    for (int j = 0; j < 4; ++j) {
        x0[j] = 0u;
        x1[j] = idx0 + (uint32_t)j * (uint32_t)NK + ks1;
    }
    round4(x0, x1, 13); round4(x0, x1, 15); round4(x0, x1, 26); round4(x0, x1, 6);
    inject4(x0, x1, ks1, ks2 + 1u);
    round4(x0, x1, 17); round4(x0, x1, 29); round4(x0, x1, 16); round4(x0, x1, 24);
    inject4(x0, x1, ks2, 0u + 2u);
    round4(x0, x1, 13); round4(x0, x1, 15); round4(x0, x1, 26); round4(x0, x1, 6);
    inject4(x0, x1, 0u, ks1 + 3u);
    round4(x0, x1, 17); round4(x0, x1, 29); round4(x0, x1, 16); round4(x0, x1, 24);
    inject4(x0, x1, ks1, ks2 + 4u);
    round4(x0, x1, 13); round4(x0, x1, 15); round4(x0, x1, 26); round4(x0, x1, 6);
#pragma unroll
    for (int j = 0; j < 4; ++j) bits[j] = (x0[j] + ks2) ^ (x1[j] + 0u + 5u);
}

__device__ __forceinline__ float fexp2(float x) {
#if __has_builtin(__builtin_amdgcn_exp2f)
    return __builtin_amdgcn_exp2f(x);
#else
    return __expf(0.6931471805599453f * x);
#endif
}

// ---------------- tiny projection: out[r][c] = x[r][:] . w[c][:] + b[c] --
__global__ void proj_kernel(const float* __restrict__ x,
                            const float* __restrict__ w,
                            const float* __restrict__ b,
                            float* __restrict__ out, int dout) {
    __shared__ __align__(16) float ws[8 * DIN];
    __shared__ float bs[8];
    const int tid = threadIdx.x;
    if (tid < dout * DIN) ws[tid] = w[tid];
    if (tid < dout) bs[tid] = b[tid];
    __syncthreads();

    const int row = blockIdx.x * BT + tid;
    const float4* xr = reinterpret_cast<const float4*>(x + (size_t)row * DIN);
    float4 xv[8];
#pragma unroll
    for (int i = 0; i < 8; ++i) xv[i] = xr[i];

    for (int c = 0; c < dout; ++c) {
        float s = bs[c];
#pragma unroll
        for (int i = 0; i < 8; ++i) {
            const float4 wv = *reinterpret_cast<const float4*>(&ws[c * DIN + i * 4]);
            s += xv[i].x * wv.x + xv[i].y * wv.y + xv[i].z * wv.z + xv[i].w * wv.w;
        }
        out[(size_t)row * dout + c] = s;
    }
}

// ---------------- fused scores+softmax+dropout+PV (k-split partials) -----
__global__ __launch_bounds__(BT) void attn_kernel(
    const float* __restrict__ q,        // [NQ][4] pre-projection output
    const float* __restrict__ k,        // [NK][4]
    const float* __restrict__ v,        // [NK][8]
    float* __restrict__ partial,        // [ksplit][NQ][12]: 8 nums, den
    int ksplit) {
    __shared__ float4 lds_k[CHUNK];
    __shared__ float4 lds_va[CHUNK];
    __shared__ float4 lds_vb[CHUNK];

    const int tid = threadIdx.x;
    const int lane = tid & 63;
    const int wave = tid >> 6;
    const int split = blockIdx.y;
    const int qbase = blockIdx.x * ROWS_PER_BLOCK + wave * RPW;
    const int klen = NK / ksplit;
    const int kstart = split * klen;

    float4 qs[RPW];
#pragma unroll
    for (int r = 0; r < RPW; ++r) {
        float4 t = *reinterpret_cast<const float4*>(q + (size_t)(qbase + r) * 4);
        qs[r] = make_float4(t.x * QSCALE, t.y * QSCALE, t.z * QSCALE, t.w * QSCALE);
    }

    float4 accA[RPW], accB[RPW];
    float den[RPW];
#pragma unroll
    for (int r = 0; r < RPW; ++r) {
        accA[r] = make_float4(0.f, 0.f, 0.f, 0.f);
        accB[r] = make_float4(0.f, 0.f, 0.f, 0.f);
        den[r] = 0.f;
    }

    const float4* ksrc = reinterpret_cast<const float4*>(k);
    const float4* vsrc = reinterpret_cast<const float4*>(v);

    for (int base = kstart; base < kstart + klen; base += CHUNK) {
        __syncthreads();
#pragma unroll
        for (int i = tid; i < CHUNK; i += BT) {
            lds_k[i]  = ksrc[base + i];
            lds_va[i] = vsrc[2 * (base + i)];
            lds_vb[i] = vsrc[2 * (base + i) + 1];
        }
        __syncthreads();

        for (int kk = lane; kk < CHUNK; kk += 64) {
            const float4 kv = lds_k[kk];
            const float4 va = lds_va[kk];
            const float4 vb = lds_vb[kk];
            const uint32_t idx0 =
                (uint32_t)qbase * (uint32_t)NK + (uint32_t)(base + kk);

            uint32_t bits[RPW];
            threefry4(idx0, bits);

            float e[RPW];
#pragma unroll
            for (int r = 0; r < RPW; ++r) {
                const float s = qs[r].x * kv.x + qs[r].y * kv.y +
                                qs[r].z * kv.z + qs[r].w * kv.w;
                e[r] = fexp2(s);
            }
#pragma unroll
            for (int r = 0; r < RPW; ++r) {
                const float w = (bits[r] < KEEP_BITS) ? e[r] : 0.0f;
                den[r] += e[r];
                accA[r].x += w * va.x; accA[r].y += w * va.y;
                accA[r].z += w * va.z; accA[r].w += w * va.w;
                accB[r].x += w * vb.x; accB[r].y += w * vb.y;
                accB[r].z += w * vb.z; accB[r].w += w * vb.w;
            }
        }
    }

    // wave-level reduction of 9 accumulators per row, write partials
#pragma unroll
    for (int r = 0; r < RPW; ++r) {
        float n0 = accA[r].x, n1 = accA[r].y, n2 = accA[r].z, n3 = accA[r].w;
        float n4 = accB[r].x, n5 = accB[r].y, n6 = accB[r].z, n7 = accB[r].w;
        float dd = den[r];
#pragma unroll
        for (int off = 32; off >= 1; off >>= 1) {
            n0 += __shfl_xor(n0, off); n1 += __shfl_xor(n1, off);
            n2 += __shfl_xor(n2, off); n3 += __shfl_xor(n3, off);
            n4 += __shfl_xor(n4, off); n5 += __shfl_xor(n5, off);
            n6 += __shfl_xor(n6, off); n7 += __shfl_xor(n7, off);
            dd += __shfl_xor(dd, off);
        }
        if (lane == 0) {
            float* p = partial + ((size_t)split * NQ + (size_t)(qbase + r)) * 12;
            p[0] = n0; p[1] = n1; p[2] = n2; p[3] = n3;
            p[4] = n4; p[5] = n5; p[6] = n6; p[7] = n7;
            p[8] = dd;
        }
    }
}

// ---------------- combine partials + final normalize ---------------------
__global__ void combine_kernel(const float* __restrict__ partial,
                               float* __restrict__ out, int ksplit) {
    const int row = blockIdx.x * 256 + threadIdx.x;
    float n[8] = {0.f, 0.f, 0.f, 0.f, 0.f, 0.f, 0.f, 0.f};
    float dd = 0.f;
    for (int s = 0; s < ksplit; ++s) {
        const float* p = partial + ((size_t)s * NQ + (size_t)row) * 12;
#pragma unroll
        for (int j = 0; j < 8; ++j) n[j] += p[j];
        dd += p[8];
    }
    const float inv = 1.0f / (0.8f * dd);
#pragma unroll
    for (int j = 0; j < 8; ++j) out[(size_t)row * 8 + j] = n[j] * inv;
}

extern "C" void kernel_launch(void* const* d_in, const int* in_sizes, int n_in,
                              void* d_out, int out_size, void* d_ws, size_t ws_size,
                              hipStream_t stream) {
    const float* x1   = (const float*)d_in[0];
    const float* x2   = (const float*)d_in[1];
    const float* wq_w = (const float*)d_in[2];
    const float* wq_b = (const float*)d_in[3];
    const float* wk_w = (const float*)d_in[4];
    const float* wk_b = (const float*)d_in[5];
    const float* wv_w = (const float*)d_in[6];
    const float* wv_b = (const float*)d_in[7];
    float* out = (float*)d_out;

    // workspace: q [8192*4] | k [8192*4] | v [8192*8] | partial [ksplit][8192][12]
    float* qws = (float*)d_ws;
    float* kws = qws + (size_t)NQ * 4;
    float* vws = kws + (size_t)NK * 4;
    float* pws = vws + (size_t)NK * 8;

    const size_t qkv_bytes = ((size_t)NQ * 4 + NK * 4 + NK * 8) * sizeof(float);
    int ksplit = 2;
    if (ws_size < qkv_bytes + (size_t)2 * NQ * 12 * sizeof(float)) ksplit = 1;

    proj_kernel<<<NQ / BT, BT, 0, stream>>>(x1, wq_w, wq_b, qws, 4);
    proj_kernel<<<NK / BT, BT, 0, stream>>>(x2, wk_w, wk_b, kws, 4);
    proj_kernel<<<NK / BT, BT, 0, stream>>>(x2, wv_w, wv_b, vws, 8);

    dim3 grid(NQ / ROWS_PER_BLOCK, ksplit);
    attn_kernel<<<grid, BT, 0, stream>>>(qws, kws, vws, pws, ksplit);

    combine_kernel<<<NQ / 256, 256, 0, stream>>>(pws, out, ksplit);
}